// Round 4
// baseline (1087.317 us; speedup 1.0000x reference)
//
#include <hip/hip_runtime.h>
#include <hip/hip_fp16.h>
#include <math.h>

#define EPSF 1e-8f
#define NN 4096
#define BB 256
#define PH ((size_t)BB * NN)

__device__ __forceinline__ float sigf(float x) { return 1.0f / (1.0f + expf(-x)); }
__device__ __forceinline__ float softplusf(float x) { return x > 20.0f ? x : log1pf(expf(x)); }
__device__ __forceinline__ float dot4(float4 a, float4 b) {
  return a.x * b.x + a.y * b.y + a.z * b.z + a.w * b.w;
}
__device__ __forceinline__ unsigned short f2bf(float x) {
  unsigned int u = __float_as_uint(x);
  unsigned int r = (u + 0x7FFF + ((u >> 16) & 1)) >> 16;
  return (unsigned short)r;
}
__device__ __forceinline__ float bf2f(unsigned int lo16) {
  return __uint_as_float(lo16 << 16);
}

// ---------------- device-scope grid barrier (AGENT atomics; per-XCD L2 safe).
// Co-residency: caller grids are far below CU capacity (see launch comments).
__device__ __forceinline__ void gbar(unsigned* arr, unsigned* rel, unsigned nb, unsigned call) {
  __syncthreads();
  if (threadIdx.x == 0) {
    unsigned old = __hip_atomic_fetch_add(arr, 1u, __ATOMIC_ACQ_REL, __HIP_MEMORY_SCOPE_AGENT);
    if (old == call * nb - 1u) {
      __hip_atomic_store(rel, call, __ATOMIC_RELEASE, __HIP_MEMORY_SCOPE_AGENT);
    } else {
      while (__hip_atomic_load(rel, __ATOMIC_ACQUIRE, __HIP_MEMORY_SCOPE_AGENT) < call) {
        __builtin_amdgcn_s_sleep(2);
      }
    }
  }
  __syncthreads();
}

__device__ __forceinline__ float gather_x(const float* __restrict__ in_data,
                                          const float* __restrict__ prev_reads,
                                          const float* __restrict__ h0,
                                          int row, int k) {
  if (k < 64) return in_data[row * 64 + k];
  if (k < 320) { int i = (k - 64) >> 6, m = (k - 64) & 63; return prev_reads[((size_t)i * 256 + row) * 64 + m]; }
  return h0[row * 512 + (k - 320)];
}

// ---------------- front: gates GEMM + LSTM + heads GEMM + params, one dispatch.
// grid 256 x 256 thr, 12.5 KB LDS -> all blocks trivially co-resident.
__global__ __launch_bounds__(256) void front_kernel(
    const float* __restrict__ in_data, const float* __restrict__ prev_reads,
    const float* __restrict__ h0, const float* __restrict__ c0,
    const float* __restrict__ W_ih, const float* __restrict__ W_hh,
    const float* __restrict__ b_ih, const float* __restrict__ b_hh,
    const float* __restrict__ W_addr, const float* __restrict__ W_ea,
    const float* __restrict__ b_addr, const float* __restrict__ b_ea,
    float* __restrict__ gates, float* __restrict__ cbuf, float* __restrict__ hbuf,
    float* __restrict__ p_raw,
    float* __restrict__ knorm, float* __restrict__ betav,
    float* __restrict__ gatev, float* __restrict__ sv,
    float* __restrict__ gammav, float* __restrict__ combo,
    float* __restrict__ scal, unsigned* __restrict__ bars) {
  __shared__ float As[16][33];
  __shared__ float Ws[16][65];
  int tid = threadIdx.x, blk = blockIdx.x;
  int tx = tid & 15, ty = tid >> 4;

  // ===== stage A: gates = [in|prev_reads|h0] @ [W_ih|W_hh]^T + biases : [256][2048]
  {
    int col0 = (blk & 31) * 64, row0 = (blk >> 5) * 32;
    float acc[2][4] = {{0,0,0,0},{0,0,0,0}};
    for (int k0 = 0; k0 < 832; k0 += 16) {
      const float* Wp; int kw, KW;
      if (k0 < 320) { Wp = W_ih; kw = k0; KW = 320; }
      else          { Wp = W_hh; kw = k0 - 320; KW = 512; }
      for (int i = tid; i < 32 * 16; i += 256) {
        int rr = i >> 4, cc = i & 15;
        As[cc][rr] = gather_x(in_data, prev_reads, h0, row0 + rr, k0 + cc);
      }
      for (int i = tid; i < 64 * 16; i += 256) {
        int rr = i >> 4, cc = i & 15;
        Ws[cc][rr] = Wp[(size_t)(col0 + rr) * KW + kw + cc];
      }
      __syncthreads();
#pragma unroll
      for (int kk = 0; kk < 16; kk++) {
        float a0 = As[kk][ty * 2 + 0], a1 = As[kk][ty * 2 + 1];
        float w0 = Ws[kk][tx * 4 + 0], w1 = Ws[kk][tx * 4 + 1];
        float w2 = Ws[kk][tx * 4 + 2], w3 = Ws[kk][tx * 4 + 3];
        acc[0][0] += a0 * w0; acc[0][1] += a0 * w1; acc[0][2] += a0 * w2; acc[0][3] += a0 * w3;
        acc[1][0] += a1 * w0; acc[1][1] += a1 * w1; acc[1][2] += a1 * w2; acc[1][3] += a1 * w3;
      }
      __syncthreads();
    }
    for (int i = 0; i < 2; i++)
      for (int j = 0; j < 4; j++) {
        int cc = col0 + tx * 4 + j;
        gates[(size_t)(row0 + ty * 2 + i) * 2048 + cc] = acc[i][j] + b_ih[cc] + b_hh[cc];
      }
  }
  gbar(bars + 0, bars + 1, 256, 1);

  // ===== stage B: LSTM elementwise (2 elems/thread)
  {
#pragma unroll
    for (int r = 0; r < 2; r++) {
      int idx = blk * 512 + r * 256 + tid;
      int b = idx >> 9, u = idx & 511;
      const float* g = gates + (size_t)b * 2048;
      float ig = sigf(g[u]), fg = sigf(g[512 + u]);
      float gg = tanhf(g[1024 + u]), og = sigf(g[1536 + u]);
      float cv = fg * c0[idx] + ig * gg;
      cbuf[idx] = cv;
      hbuf[idx] = og * tanhf(cv);
    }
  }
  gbar(bars + 0, bars + 1, 256, 2);

  // ===== stage C: p_raw = c @ [W_addr(560)|W_ea(512)]^T + bias : [256][1072] (blocks 0..135)
  if (blk < 136) {
    int col0 = (blk % 17) * 64, row0 = (blk / 17) * 32;
    float acc[2][4] = {{0,0,0,0},{0,0,0,0}};
    for (int k0 = 0; k0 < 512; k0 += 16) {
      for (int i = tid; i < 32 * 16; i += 256) {
        int rr = i >> 4, cc = i & 15;
        As[cc][rr] = cbuf[(size_t)(row0 + rr) * 512 + k0 + cc];
      }
      for (int i = tid; i < 64 * 16; i += 256) {
        int rr = i >> 4, cc = i & 15;
        int col = col0 + rr;
        float v = 0.f;
        if (col < 560) v = W_addr[(size_t)col * 512 + k0 + cc];
        else if (col < 1072) v = W_ea[(size_t)(col - 560) * 512 + k0 + cc];
        Ws[cc][rr] = v;
      }
      __syncthreads();
#pragma unroll
      for (int kk = 0; kk < 16; kk++) {
        float a0 = As[kk][ty * 2 + 0], a1 = As[kk][ty * 2 + 1];
        float w0 = Ws[kk][tx * 4 + 0], w1 = Ws[kk][tx * 4 + 1];
        float w2 = Ws[kk][tx * 4 + 2], w3 = Ws[kk][tx * 4 + 3];
        acc[0][0] += a0 * w0; acc[0][1] += a0 * w1; acc[0][2] += a0 * w2; acc[0][3] += a0 * w3;
        acc[1][0] += a1 * w0; acc[1][1] += a1 * w1; acc[1][2] += a1 * w2; acc[1][3] += a1 * w3;
      }
      __syncthreads();
    }
    for (int i = 0; i < 2; i++)
      for (int j = 0; j < 4; j++) {
        int col = col0 + tx * 4 + j;
        if (col < 1072) {
          float bias = col < 560 ? b_addr[col] : b_ea[col - 560];
          p_raw[(size_t)(row0 + ty * 2 + i) * 1072 + col] = acc[i][j] + bias;
        }
      }
  }
  gbar(bars + 0, bars + 1, 256, 3);

  // ===== stage D: per-b params (threads 0..63, one wave)
  if (tid < 64) {
    int b = blk, m = tid;
    const float* p = p_raw + (size_t)b * 1072;
    float kv[7];
#pragma unroll
    for (int hi = 0; hi < 7; hi++) {
      float k = tanhf(p[hi * 70 + m]);
      kv[hi] = k;
      float s = k * k;
#pragma unroll
      for (int d = 1; d < 64; d <<= 1) s += __shfl_xor(s, d);
      if (m == 0) {
        int hb = hi * BB + b;
        knorm[hb] = sqrtf(s);
        betav[hb] = softplusf(p[hi * 70 + 64]);
        gatev[hb] = sigf(p[hi * 70 + 65]);
        float a0 = p[hi * 70 + 66], a1 = p[hi * 70 + 67], a2 = p[hi * 70 + 68];
        float mm = fmaxf(a0, fmaxf(a1, a2));
        float e0 = expf(a0 - mm), e1 = expf(a1 - mm), e2 = expf(a2 - mm);
        float es = e0 + e1 + e2;
        sv[hb * 3 + 0] = e0 / es; sv[hb * 3 + 1] = e1 / es; sv[hb * 3 + 2] = e2 / es;
        gammav[hb] = 1.0f + softplusf(p[hi * 70 + 69]);
      }
    }
    float e1 = sigf(p[560 + 0 * 128 + m]),  a1v = tanhf(p[560 + 0 * 128 + 64 + m]);
    float e3 = sigf(p[560 + 1 * 128 + m]),  a3v = tanhf(p[560 + 1 * 128 + 64 + m]);
    float e5 = sigf(p[560 + 2 * 128 + m]),  a5v = tanhf(p[560 + 2 * 128 + 64 + m]);
    size_t bm = (size_t)b * 64 + m;
    combo[0 * 16384 + bm] = kv[0];  combo[1 * 16384 + bm] = kv[1];
    combo[2 * 16384 + bm] = kv[2];  combo[3 * 16384 + bm] = e1 * kv[2];
    combo[4 * 16384 + bm] = kv[3];  combo[5 * 16384 + bm] = e1 * kv[3];
    combo[6 * 16384 + bm] = a1v;    combo[7 * 16384 + bm] = e1 * a1v;
    combo[8 * 16384 + bm] = e1;     combo[9 * 16384 + bm] = e1 * e1;
    combo[10 * 16384 + bm] = kv[4]; combo[11 * 16384 + bm] = kv[5];
    combo[12 * 16384 + bm] = kv[6]; combo[13 * 16384 + bm] = e5 * kv[6];
    combo[14 * 16384 + bm] = a5v;   combo[15 * 16384 + bm] = e5 * a5v;
    combo[16 * 16384 + bm] = e5;    combo[17 * 16384 + bm] = e5 * e5;
    combo[18 * 16384 + bm] = e3;    combo[19 * 16384 + bm] = a3v;
    float s0 = a1v * kv[2], s1 = a1v * kv[3], s2 = a1v * a1v, s3 = a5v * kv[6], s4 = a5v * a5v;
#pragma unroll
    for (int d = 1; d < 64; d <<= 1) {
      s0 += __shfl_xor(s0, d); s1 += __shfl_xor(s1, d); s2 += __shfl_xor(s2, d);
      s3 += __shfl_xor(s3, d); s4 += __shfl_xor(s4, d);
    }
    if (m == 0) {
      scal[b * 8 + 0] = s0; scal[b * 8 + 1] = s1; scal[b * 8 + 2] = s2;
      scal[b * 8 + 3] = s3; scal[b * 8 + 4] = s4;
    }
  }
}

#define CL(j, q) (*(const float4*)(cb + (j) * 64 + (q) * 4))

// ---------------- phase 1: LDS-staged coalesced. fp32 stream -> bf16 shadow + 9 planes
__global__ __launch_bounds__(256) void phase1_kernel(
    const float* __restrict__ mem, const float* __restrict__ combo,
    const float* __restrict__ scal, const float* __restrict__ knorm,
    const float* __restrict__ betav, unsigned short* __restrict__ mem_bf,
    __half* __restrict__ P) {
  __shared__ float cb[640];
  __shared__ float4 tile[128 * 16];   // 32 KB, XOR-swizzled rows
  int b = blockIdx.y, tid = threadIdx.x;
  for (int i = tid; i < 640; i += 256)
    cb[i] = combo[(size_t)(i >> 6) * 16384 + b * 64 + (i & 63)];
  int n0 = blockIdx.x * 128;
  size_t bo = (size_t)b * NN;
  const float4* src = (const float4*)mem + (bo + n0) * 16;
  ushort4* dst = (ushort4*)mem_bf + (bo + n0) * 16;
#pragma unroll
  for (int i = 0; i < 8; i++) {
    int idx = tid + i * 256;
    float4 v = src[idx];
    int r = idx >> 4, q = idx & 15;
    tile[r * 16 + (q ^ (r & 15))] = v;
    ushort4 o;
    o.x = f2bf(v.x); o.y = f2bf(v.y); o.z = f2bf(v.z); o.w = f2bf(v.w);
    dst[idx] = o;
  }
  __syncthreads();
  float kn0 = knorm[b], be0 = betav[b];
  float kn1 = knorm[BB + b], be1 = betav[BB + b];
  float cak2 = scal[b * 8 + 0], cak3 = scal[b * 8 + 1], caa1 = scal[b * 8 + 2];
  int row = tid >> 1, half = tid & 1;
  float a[11];
#pragma unroll
  for (int k = 0; k < 11; k++) a[k] = 0.f;
#pragma unroll
  for (int j = 0; j < 8; j++) {
    int q = half * 8 + j;
    float4 v = tile[row * 16 + (q ^ (row & 15))];
    float4 sq = make_float4(v.x * v.x, v.y * v.y, v.z * v.z, v.w * v.w);
    a[0] += dot4(v, CL(0, q)); a[1] += dot4(v, CL(1, q));
    a[2] += dot4(v, CL(2, q)); a[3] += dot4(v, CL(3, q));
    a[4] += dot4(v, CL(4, q)); a[5] += dot4(v, CL(5, q));
    a[6] += dot4(v, CL(6, q)); a[7] += dot4(v, CL(7, q));
    a[8] += sq.x + sq.y + sq.z + sq.w;
    a[9] += dot4(sq, CL(8, q)); a[10] += dot4(sq, CL(9, q));
  }
#pragma unroll
  for (int k = 0; k < 11; k++) a[k] += __shfl_xor(a[k], 1);
  if (half == 0) {
    int n = n0 + row;
    float rn = sqrtf(a[8]);
    P[0 * PH + bo + n] = __float2half(be0 * a[0] / (rn * kn0 + EPSF));
    P[1 * PH + bo + n] = __float2half(be1 * a[1] / (rn * kn1 + EPSF));
    P[2 * PH + bo + n] = __float2half(a[2]);
    P[3 * PH + bo + n] = __float2half(a[3] - cak2);
    P[4 * PH + bo + n] = __float2half(a[4]);
    P[5 * PH + bo + n] = __float2half(a[5] - cak3);
    P[6 * PH + bo + n] = __float2half(a[8]);
    P[7 * PH + bo + n] = __float2half(a[9] - a[6]);
    P[8 * PH + bo + n] = __float2half(a[10] - 2.f * a[7] + caa1);
  }
}

// ---------------- chain core: score -> softmax -> interp -> shift -> sharpen -> w_g
__device__ void chain_core(int tid, int b, int head,
    const __half* __restrict__ SC, const __half* __restrict__ Da,
    const __half* __restrict__ Dbc, const __half* __restrict__ S0p,
    const __half* __restrict__ T1p, const __half* __restrict__ T2p,
    const __half* __restrict__ ug, __half* __restrict__ wout,
    float* wg, float* red,
    const float* __restrict__ knorm, const float* __restrict__ betav,
    const float* __restrict__ gatev, const float* __restrict__ sv,
    const float* __restrict__ gammav, const float* __restrict__ prev_w) {
  int lane = tid & 63, wv = tid >> 6;
  int hb = head * BB + b;
  float kn = knorm[hb], be = betav[hb], ga = gatev[hb], gm = gammav[hb];
  float s0 = sv[hb * 3 + 0], s1 = sv[hb * 3 + 1], s2 = sv[hb * 3 + 2];
  size_t bo = (size_t)b * NN;
  const float* pw = prev_w + (size_t)head * PH + bo;
  float sc[8];
  float mx = -1e30f;
#pragma unroll
  for (int i = 0; i < 8; i++) {
    int n = tid + i * 512;
    float scv;
    if (SC != nullptr) {
      scv = __half2float(SC[bo + n]);
    } else {
      float u = __half2float(ug[n]);
      float d = __half2float(Da[bo + n]) - u * __half2float(Dbc[bo + n]);
      float nn2 = __half2float(S0p[bo + n]) - 2.f * u * __half2float(T1p[bo + n])
                + u * u * __half2float(T2p[bo + n]);
      nn2 = fmaxf(nn2, 0.f);
      scv = be * d / (sqrtf(nn2) * kn + EPSF);
    }
    sc[i] = scv; mx = fmaxf(mx, scv);
  }
#pragma unroll
  for (int m = 1; m < 64; m <<= 1) mx = fmaxf(mx, __shfl_xor(mx, m));
  if (lane == 0) red[wv] = mx;
  __syncthreads();
  mx = red[0];
#pragma unroll
  for (int w = 1; w < 8; w++) mx = fmaxf(mx, red[w]);
  float sum = 0.f;
#pragma unroll
  for (int i = 0; i < 8; i++) { sc[i] = __expf(sc[i] - mx); sum += sc[i]; }
#pragma unroll
  for (int m = 1; m < 64; m <<= 1) sum += __shfl_xor(sum, m);
  if (lane == 0) red[8 + wv] = sum;
  __syncthreads();
  sum = 0.f;
#pragma unroll
  for (int w = 0; w < 8; w++) sum += red[8 + w];
  float inv = 1.0f / sum;
#pragma unroll
  for (int i = 0; i < 8; i++) {
    int n = tid + i * 512;
    wg[n] = ga * (sc[i] * inv) + (1.f - ga) * pw[n];
  }
  __syncthreads();
  float wp[8];
  float sum2 = 0.f;
#pragma unroll
  for (int i = 0; i < 8; i++) {
    int n = tid + i * 512;
    float wsv = s0 * wg[(n + NN - 1) & (NN - 1)] + s1 * wg[n] + s2 * wg[(n + 1) & (NN - 1)];
    wp[i] = __powf(wsv, gm);
    sum2 += wp[i];
  }
#pragma unroll
  for (int m = 1; m < 64; m <<= 1) sum2 += __shfl_xor(sum2, m);
  if (lane == 0) red[16 + wv] = sum2;
  __syncthreads();
  sum2 = 0.f;
#pragma unroll
  for (int w = 0; w < 8; w++) sum2 += red[16 + w];
  float invs = 1.0f / (sum2 + EPSF);
#pragma unroll
  for (int i = 0; i < 8; i++) {
    int n = tid + i * 512;
    wout[n] = __float2half(wp[i] * invs);
  }
  __syncthreads();   // protect wg/red reuse across stages
}

// ---------------- chains 0,1 then (gbar) 2,3. grid (256,2) x 512 thr.
// 8 waves + 16.5KB LDS -> 4 blocks/CU capacity, 512 blocks co-resident.
__global__ __launch_bounds__(512) void chains01_kernel(
    const __half* __restrict__ P, __half* __restrict__ w_g,
    const float* __restrict__ knorm, const float* __restrict__ betav,
    const float* __restrict__ gatev, const float* __restrict__ sv,
    const float* __restrict__ gammav, const float* __restrict__ prev_w,
    unsigned* __restrict__ bars) {
  __shared__ float wg[NN];
  __shared__ float red[24];
  int b = blockIdx.x, hy = blockIdx.y, tid = threadIdx.x;
  // stage 1: heads {0,1}, SC-path
  chain_core(tid, b, hy, P + (size_t)hy * PH, nullptr, nullptr, nullptr, nullptr, nullptr,
             nullptr, w_g + ((size_t)hy * BB + b) * NN, wg, red,
             knorm, betav, gatev, sv, gammav, prev_w);
  gbar(bars + 0, bars + 1, 512, 1);
  // stage 2: heads {2,3}, D-path with u = w1
  chain_core(tid, b, 2 + hy, nullptr,
             P + (size_t)(2 + 2 * hy) * PH, P + (size_t)(3 + 2 * hy) * PH,
             P + 6 * PH, P + 7 * PH, P + 8 * PH,
             w_g + ((size_t)1 * BB + b) * NN, w_g + ((size_t)(2 + hy) * BB + b) * NN, wg, red,
             knorm, betav, gatev, sv, gammav, prev_w);
}

// ---------------- chains 4,5 then (gbar) 6. grid (256,2) x 512 thr.
__global__ __launch_bounds__(512) void chains23_kernel(
    const __half* __restrict__ P, __half* __restrict__ w_g,
    const float* __restrict__ knorm, const float* __restrict__ betav,
    const float* __restrict__ gatev, const float* __restrict__ sv,
    const float* __restrict__ gammav, const float* __restrict__ prev_w,
    unsigned* __restrict__ bars) {
  __shared__ float wg[NN];
  __shared__ float red[24];
  int b = blockIdx.x, hy = blockIdx.y, tid = threadIdx.x;
  // stage 1: heads {4,5}, SC-path (phase2 planes 0,1)
  chain_core(tid, b, 4 + hy, P + (size_t)hy * PH, nullptr, nullptr, nullptr, nullptr, nullptr,
             nullptr, w_g + ((size_t)(4 + hy) * BB + b) * NN, wg, red,
             knorm, betav, gatev, sv, gammav, prev_w);
  gbar(bars + 0, bars + 1, 512, 1);
  // stage 2: head 6, D-path with u = w5 (hy==0 blocks only)
  if (hy == 0) {
    chain_core(tid, b, 6, nullptr, P + 2 * PH, P + 3 * PH,
               P + 4 * PH, P + 5 * PH, P + 6 * PH,
               w_g + ((size_t)5 * BB + b) * NN, w_g + ((size_t)6 * BB + b) * NN, wg, red,
               knorm, betav, gatev, sv, gammav, prev_w);
  }
}

// ---------------- phase 2: LDS-staged coalesced. bf16 stream, m2 in regs, 7 planes
__global__ __launch_bounds__(256) void phase2_kernel(
    const unsigned short* __restrict__ mem_bf, const float* __restrict__ combo,
    const float* __restrict__ scal, const float* __restrict__ knorm,
    const float* __restrict__ betav, const __half* __restrict__ w_g,
    __half* __restrict__ P) {
  __shared__ float cb[1280];
  __shared__ uint4 tileb[128 * 8];
  int b = blockIdx.y, tid = threadIdx.x;
  for (int i = tid; i < 1280; i += 256)
    cb[i] = combo[(size_t)(i >> 6) * 16384 + b * 64 + (i & 63)];
  int n0 = blockIdx.x * 128;
  size_t bo = (size_t)b * NN;
  const uint4* src = (const uint4*)mem_bf + (bo + n0) * 8;
#pragma unroll
  for (int i = 0; i < 4; i++) {
    int idx = tid + i * 256;
    uint4 u = src[idx];
    int r = idx >> 3, g = idx & 7;
    tileb[r * 8 + (g ^ (r & 7))] = u;
  }
  __syncthreads();
  float kn4 = knorm[4 * BB + b], be4 = betav[4 * BB + b];
  float kn5 = knorm[5 * BB + b], be5 = betav[5 * BB + b];
  float cak6 = scal[b * 8 + 3], caa5 = scal[b * 8 + 4];
  int row = tid >> 1, half = tid & 1;
  int n = n0 + row;
  float u1 = __half2float(w_g[((size_t)1 * BB + b) * NN + n]);
  float u3 = __half2float(w_g[((size_t)3 * BB + b) * NN + n]);
  float t[9];
#pragma unroll
  for (int k = 0; k < 9; k++) t[k] = 0.f;
#pragma unroll
  for (int j = 0; j < 4; j++) {
    int g = half * 4 + j;
    uint4 uv = tileb[row * 8 + (g ^ (row & 7))];
#pragma unroll
    for (int h = 0; h < 2; h++) {
      unsigned int pa = h ? uv.z : uv.x;
      unsigned int pb = h ? uv.w : uv.y;
      float4 v;
      v.x = bf2f(pa & 0xFFFFu); v.y = bf2f(pa >> 16);
      v.z = bf2f(pb & 0xFFFFu); v.w = bf2f(pb >> 16);
      int q = g * 2 + h;
      float4 e1v = CL(8, q), a1v = CL(6, q), e3v = CL(18, q), a3v = CL(19, q);
      float4 m1, m2;
      m1.x = v.x * (1.f - u1 * e1v.x) + u1 * a1v.x;
      m1.y = v.y * (1.f - u1 * e1v.y) + u1 * a1v.y;
      m1.z = v.z * (1.f - u1 * e1v.z) + u1 * a1v.z;
      m1.w = v.w * (1.f - u1 * e1v.w) + u1 * a1v.w;
      m2.x = m1.x * (1.f - u3 * e3v.x) + u3 * a3v.x;
      m2.y = m1.y * (1.f - u3 * e3v.y) + u3 * a3v.y;
      m2.z = m1.z * (1.f - u3 * e3v.z) + u3 * a3v.z;
      m2.w = m1.w * (1.f - u3 * e3v.w) + u3 * a3v.w;
      float4 sq = make_float4(m2.x * m2.x, m2.y * m2.y, m2.z * m2.z, m2.w * m2.w);
      t[0] += dot4(m2, CL(10, q)); t[1] += dot4(m2, CL(11, q));
      t[2] += dot4(m2, CL(12, q)); t[3] += dot4(m2, CL(13, q));
      t[4] += dot4(m2, CL(14, q)); t[5] += dot4(m2, CL(15, q));
      t[6] += sq.x + sq.y + sq.z + sq.w;
      t[7] += dot4(sq, CL(16, q)); t[8] += dot4(sq, CL(17, q));
    }
  }
#pragma unroll
  for (int k = 0; k < 9; k++) t[k] += __shfl_xor(t[k], 1);
  if (half == 0) {
    float rn = sqrtf(t[6]);
    P[0 * PH + bo + n] = __float2half(be4 * t[0] / (rn * kn4 + EPSF));
    P[1 * PH + bo + n] = __float2half(be5 * t[1] / (rn * kn5 + EPSF));
    P[2 * PH + bo + n] = __float2half(t[2]);
    P[3 * PH + bo + n] = __float2half(t[3] - cak6);
    P[4 * PH + bo + n] = __float2half(t[6]);
    P[5 * PH + bo + n] = __float2half(t[7] - t[4]);
    P[6 * PH + bo + n] = __float2half(t[8] - 2.f * t[5] + caa5);
  }
}

// ---------------- phase 3: the four reads. grid (8,256) x 256 thr, atomicAdd partials
__global__ __launch_bounds__(256) void phase3_kernel(
    const unsigned short* __restrict__ mem_bf, const float* __restrict__ combo,
    const __half* __restrict__ w_g, float* __restrict__ reads) {
  __shared__ float cb[1280];
  __shared__ __half ws[7 * 512];
  __shared__ float sred[4 * 4 * 16 * 4];
  int b = blockIdx.y, chunk = blockIdx.x, tid = threadIdx.x;
  for (int i = tid; i < 1280; i += 256)
    cb[i] = combo[(size_t)(i >> 6) * 16384 + b * 64 + (i & 63)];
  int nbase = chunk * 512;
  for (int i = tid; i < 7 * 512; i += 256) {
    int hh = i >> 9, nn = i & 511;
    ws[i] = w_g[((size_t)hh * BB + b) * NN + nbase + nn];
  }
  __syncthreads();
  int wv = tid >> 6, lane = tid & 63, q = lane & 15, rl = lane >> 4;
  float4 e1v = CL(8, q), a1v = CL(6, q), e3v = CL(18, q), a3v = CL(19, q);
  float4 e5v = CL(16, q), a5v = CL(14, q);
  size_t bo = (size_t)b * NN;
  const ushort4* mbr = (const ushort4*)mem_bf + bo * 16;
  float A[4][4];
#pragma unroll
  for (int j = 0; j < 4; j++)
#pragma unroll
    for (int cmp = 0; cmp < 4; cmp++) A[j][cmp] = 0.f;
#pragma unroll 4
  for (int t = 0; t < 32; t++) {
    int nl = t * 16 + wv * 4 + rl;
    int n = nbase + nl;
    ushort4 uv = mbr[(size_t)n * 16 + q];
    float vx = bf2f(uv.x), vy = bf2f(uv.y), vz = bf2f(uv.z), vw = bf2f(uv.w);
    float w0v = __half2float(ws[0 * 512 + nl]);
    float u1  = __half2float(ws[1 * 512 + nl]);
    float w2v = __half2float(ws[2 * 512 + nl]);
    float u3  = __half2float(ws[3 * 512 + nl]);
    float w4v = __half2float(ws[4 * 512 + nl]);
    float u5  = __half2float(ws[5 * 512 + nl]);
    float w6v = __half2float(ws[6 * 512 + nl]);
    A[0][0] += w0v * vx; A[0][1] += w0v * vy; A[0][2] += w0v * vz; A[0][3] += w0v * vw;
    float m1x = vx * (1.f - u1 * e1v.x) + u1 * a1v.x;
    float m1y = vy * (1.f - u1 * e1v.y) + u1 * a1v.y;
    float m1z = vz * (1.f - u1 * e1v.z) + u1 * a1v.z;
    float m1w = vw * (1.f - u1 * e1v.w) + u1 * a1v.w;
    A[1][0] += w2v * m1x; A[1][1] += w2v * m1y; A[1][2] += w2v * m1z; A[1][3] += w2v * m1w;
    float m2x = m1x * (1.f - u3 * e3v.x) + u3 * a3v.x;
    float m2y = m1y * (1.f - u3 * e3v.y) + u3 * a3v.y;
    float m2z = m1z * (1.f - u3 * e3v.z) + u3 * a3v.z;
    float m2w = m1w * (1.f - u3 * e3v.w) + u3 * a3v.w;
    A[2][0] += w4v * m2x; A[2][1] += w4v * m2y; A[2][2] += w4v * m2z; A[2][3] += w4v * m2w;
    float m3x = m2x * (1.f - u5 * e5v.x) + u5 * a5v.x;
    float m3y = m2y * (1.f - u5 * e5v.y) + u5 * a5v.y;
    float m3z = m2z * (1.f - u5 * e5v.z) + u5 * a5v.z;
    float m3w = m2w * (1.f - u5 * e5v.w) + u5 * a5v.w;
    A[3][0] += w6v * m3x; A[3][1] += w6v * m3y; A[3][2] += w6v * m3z; A[3][3] += w6v * m3w;
  }
#pragma unroll
  for (int j = 0; j < 4; j++)
#pragma unroll
    for (int cmp = 0; cmp < 4; cmp++) {
      float x = A[j][cmp];
      x += __shfl_xor(x, 16);
      x += __shfl_xor(x, 32);
      A[j][cmp] = x;
    }
  if (rl == 0)
#pragma unroll
    for (int j = 0; j < 4; j++)
#pragma unroll
      for (int cmp = 0; cmp < 4; cmp++)
        sred[((j * 4 + wv) * 16 + q) * 4 + cmp] = A[j][cmp];
  __syncthreads();
  if (tid < 256) {
    int j = tid >> 6, qq = (tid >> 2) & 15, cc = tid & 3;
    float s = 0.f;
#pragma unroll
    for (int w = 0; w < 4; w++) s += sred[((j * 4 + w) * 16 + qq) * 4 + cc];
    atomicAdd(&reads[(size_t)j * 16384 + b * 64 + qq * 4 + cc], s);
  }
}

// ---------------- out = sigmoid([h|reads] @ W_out^T + b_out) : [256][64]
__global__ __launch_bounds__(256) void gemm_out_kernel(
    const float* __restrict__ h, const float* __restrict__ reads,
    const float* __restrict__ W_out, const float* __restrict__ b_out,
    float* __restrict__ out) {
  __shared__ float As[16][33];
  __shared__ float Ws[16][65];
  int tid = threadIdx.x, tx = tid & 15, ty = tid >> 4;
  int row0 = blockIdx.y * 32;
  float acc[2][4] = {{0,0,0,0},{0,0,0,0}};
  for (int k0 = 0; k0 < 768; k0 += 16) {
    for (int i = tid; i < 32 * 16; i += 256) {
      int rr = i >> 4, cc = i & 15;
      int row = row0 + rr, k = k0 + cc;
      float v;
      if (k < 512) v = h[row * 512 + k];
      else { int slot = (k - 512) >> 6, m = (k - 512) & 63; v = reads[((size_t)slot * 256 + row) * 64 + m]; }
      As[cc][rr] = v;
    }
    for (int i = tid; i < 64 * 16; i += 256) {
      int rr = i >> 4, cc = i & 15;
      Ws[cc][rr] = W_out[(size_t)rr * 768 + k0 + cc];
    }
    __syncthreads();
#pragma unroll
    for (int kk = 0; kk < 16; kk++) {
      float a0 = As[kk][ty * 2 + 0], a1 = As[kk][ty * 2 + 1];
      float w0 = Ws[kk][tx * 4 + 0], w1 = Ws[kk][tx * 4 + 1];
      float w2 = Ws[kk][tx * 4 + 2], w3 = Ws[kk][tx * 4 + 3];
      acc[0][0] += a0 * w0; acc[0][1] += a0 * w1; acc[0][2] += a0 * w2; acc[0][3] += a0 * w3;
      acc[1][0] += a1 * w0; acc[1][1] += a1 * w1; acc[1][2] += a1 * w2; acc[1][3] += a1 * w3;
    }
    __syncthreads();
  }
  for (int i = 0; i < 2; i++)
    for (int j = 0; j < 4; j++) {
      int cc = tx * 4 + j;
      out[(size_t)(row0 + ty * 2 + i) * 64 + cc] = sigf(acc[i][j] + b_out[cc]);
    }
}

extern "C" void kernel_launch(void* const* d_in, const int* in_sizes, int n_in,
                              void* d_out, int out_size, void* d_ws, size_t ws_size,
                              hipStream_t stream) {
  const float* in_data = (const float*)d_in[0];
  const float* memory  = (const float*)d_in[1];
  const float* h0      = (const float*)d_in[2];
  const float* c0      = (const float*)d_in[3];
  const float* prev_w  = (const float*)d_in[4];
  const float* prev_r  = (const float*)d_in[5];
  const float* W_ih    = (const float*)d_in[6];
  const float* b_ih    = (const float*)d_in[7];
  const float* W_hh    = (const float*)d_in[8];
  const float* b_hh    = (const float*)d_in[9];
  const float* W_out   = (const float*)d_in[10];
  const float* b_out   = (const float*)d_in[11];
  const float* W_addr  = (const float*)d_in[12];
  const float* b_addr  = (const float*)d_in[13];
  const float* W_ea    = (const float*)d_in[14];
  const float* b_ea    = (const float*)d_in[15];
  float* out = (float*)d_out;
  (void)in_sizes; (void)n_in; (void)out_size; (void)ws_size;

  float* ws = (float*)d_ws;
  size_t off = 0;
  auto alloc = [&](size_t n) { float* p = ws + off; off += (n + 63) & ~(size_t)63; return p; };
  float* gates  = alloc(256 * 2048);
  float* cbuf   = alloc(256 * 512);
  float* hbuf   = alloc(256 * 512);
  float* p_raw  = alloc(256 * 1072);
  float* knorm  = alloc(8 * 256);
  float* betav  = alloc(8 * 256);
  float* gatev  = alloc(8 * 256);
  float* sv     = alloc(8 * 256 * 3);
  float* gammav = alloc(8 * 256);
  float* combo  = alloc(20 * 16384);
  float* scal   = alloc(256 * 8);
  __half* P     = (__half*)alloc(9 * PH / 2);           // 9 fp16 planes
  float* reads  = alloc(4 * 16384);                     // zeroed below
  unsigned* bars = (unsigned*)alloc(64);                // 3 barrier pairs, zeroed below
  unsigned short* mem_bf = (unsigned short*)alloc(33554432); // 128 MB bf16 copy
  __half* w_g   = (__half*)alloc(7 * BB * NN / 2);      // 7 head-weight planes fp16

  // zero reads (phase3 atomics) + barrier state in one shot; reads is 64-aligned
  (void)hipMemsetAsync(reads, 0, (4 * 16384 + 64) * sizeof(float), stream);

  front_kernel<<<256, 256, 0, stream>>>(in_data, prev_r, h0, c0, W_ih, W_hh, b_ih, b_hh,
                                        W_addr, W_ea, b_addr, b_ea,
                                        gates, cbuf, hbuf, p_raw,
                                        knorm, betav, gatev, sv, gammav, combo, scal,
                                        bars + 0);
  phase1_kernel<<<dim3(32, 256), 256, 0, stream>>>(memory, combo, scal, knorm, betav, mem_bf, P);
  chains01_kernel<<<dim3(256, 2), 512, 0, stream>>>(P, w_g, knorm, betav, gatev, sv, gammav, prev_w, bars + 2);
  phase2_kernel<<<dim3(32, 256), 256, 0, stream>>>(mem_bf, combo, scal, knorm, betav, w_g, P);
  chains23_kernel<<<dim3(256, 2), 512, 0, stream>>>(P, w_g, knorm, betav, gatev, sv, gammav, prev_w, bars + 4);
  phase3_kernel<<<dim3(8, 256), 256, 0, stream>>>(mem_bf, combo, w_g, reads);
  gemm_out_kernel<<<dim3(1, 8), 256, 0, stream>>>(hbuf, reads, W_out, b_out, out);
}

// Round 5
// 882.274 us; speedup vs baseline: 1.2324x; 1.2324x over previous
//
#include <hip/hip_runtime.h>
#include <hip/hip_fp16.h>
#include <math.h>

#define EPSF 1e-8f
#define NN 4096
#define BB 256
#define PH ((size_t)BB * NN)

__device__ __forceinline__ float sigf(float x) { return 1.0f / (1.0f + expf(-x)); }
__device__ __forceinline__ float softplusf(float x) { return x > 20.0f ? x : log1pf(expf(x)); }
__device__ __forceinline__ float dot4(float4 a, float4 b) {
  return a.x * b.x + a.y * b.y + a.z * b.z + a.w * b.w;
}
__device__ __forceinline__ unsigned short f2bf(float x) {
  unsigned int u = __float_as_uint(x);
  unsigned int r = (u + 0x7FFF + ((u >> 16) & 1)) >> 16;
  return (unsigned short)r;
}
__device__ __forceinline__ float bf2f(unsigned int lo16) {
  return __uint_as_float(lo16 << 16);
}

// ---------------- gates = [in|prev_reads|h0] @ [W_ih|W_hh]^T + b_ih + b_hh : [256][2048]
__device__ __forceinline__ float gather_x(const float* __restrict__ in_data,
                                          const float* __restrict__ prev_reads,
                                          const float* __restrict__ h0,
                                          int row, int k) {
  if (k < 64) return in_data[row * 64 + k];
  if (k < 320) { int i = (k - 64) >> 6, m = (k - 64) & 63; return prev_reads[((size_t)i * 256 + row) * 64 + m]; }
  return h0[row * 512 + (k - 320)];
}

__global__ __launch_bounds__(256) void gemm_gates_kernel(
    const float* __restrict__ in_data, const float* __restrict__ prev_reads,
    const float* __restrict__ h0, const float* __restrict__ W_ih,
    const float* __restrict__ W_hh, const float* __restrict__ b_ih,
    const float* __restrict__ b_hh, float* __restrict__ gates) {
  __shared__ float As[16][33];
  __shared__ float Ws[16][65];
  int tid = threadIdx.x, tx = tid & 15, ty = tid >> 4;
  int row0 = blockIdx.y * 32, col0 = blockIdx.x * 64;
  float acc[2][4] = {{0,0,0,0},{0,0,0,0}};
  for (int k0 = 0; k0 < 832; k0 += 16) {
    const float* Wp; int kw, KW;
    if (k0 < 320) { Wp = W_ih; kw = k0; KW = 320; }
    else          { Wp = W_hh; kw = k0 - 320; KW = 512; }
    for (int i = tid; i < 32 * 16; i += 256) {
      int rr = i >> 4, cc = i & 15;
      As[cc][rr] = gather_x(in_data, prev_reads, h0, row0 + rr, k0 + cc);
    }
    for (int i = tid; i < 64 * 16; i += 256) {
      int rr = i >> 4, cc = i & 15;
      Ws[cc][rr] = Wp[(size_t)(col0 + rr) * KW + kw + cc];
    }
    __syncthreads();
#pragma unroll
    for (int kk = 0; kk < 16; kk++) {
      float a0 = As[kk][ty * 2 + 0], a1 = As[kk][ty * 2 + 1];
      float w0 = Ws[kk][tx * 4 + 0], w1 = Ws[kk][tx * 4 + 1];
      float w2 = Ws[kk][tx * 4 + 2], w3 = Ws[kk][tx * 4 + 3];
      acc[0][0] += a0 * w0; acc[0][1] += a0 * w1; acc[0][2] += a0 * w2; acc[0][3] += a0 * w3;
      acc[1][0] += a1 * w0; acc[1][1] += a1 * w1; acc[1][2] += a1 * w2; acc[1][3] += a1 * w3;
    }
    __syncthreads();
  }
  for (int i = 0; i < 2; i++)
    for (int j = 0; j < 4; j++) {
      int cc = col0 + tx * 4 + j;
      gates[(size_t)(row0 + ty * 2 + i) * 2048 + cc] = acc[i][j] + b_ih[cc] + b_hh[cc];
    }
}

__global__ void lstm_elem_kernel(const float* __restrict__ gates,
                                 const float* __restrict__ c0,
                                 float* __restrict__ c, float* __restrict__ h) {
  int idx = blockIdx.x * 256 + threadIdx.x;
  if (idx >= 256 * 512) return;
  int b = idx >> 9, u = idx & 511;
  const float* g = gates + (size_t)b * 2048;
  float ig = sigf(g[u]), fg = sigf(g[512 + u]);
  float gg = tanhf(g[1024 + u]), og = sigf(g[1536 + u]);
  float cv = fg * c0[idx] + ig * gg;
  c[idx] = cv;
  h[idx] = og * tanhf(cv);
}

// ---------------- p_raw = c @ [W_addr(560)|W_ea(512)]^T + bias : [256][1072]
__global__ __launch_bounds__(256) void gemm_heads_kernel(
    const float* __restrict__ C, const float* __restrict__ W_addr,
    const float* __restrict__ W_ea, const float* __restrict__ b_addr,
    const float* __restrict__ b_ea, float* __restrict__ p_raw) {
  __shared__ float As[16][33];
  __shared__ float Ws[16][65];
  int tid = threadIdx.x, tx = tid & 15, ty = tid >> 4;
  int row0 = blockIdx.y * 32, col0 = blockIdx.x * 64;
  float acc[2][4] = {{0,0,0,0},{0,0,0,0}};
  for (int k0 = 0; k0 < 512; k0 += 16) {
    for (int i = tid; i < 32 * 16; i += 256) {
      int rr = i >> 4, cc = i & 15;
      As[cc][rr] = C[(size_t)(row0 + rr) * 512 + k0 + cc];
    }
    for (int i = tid; i < 64 * 16; i += 256) {
      int rr = i >> 4, cc = i & 15;
      int col = col0 + rr;
      float v = 0.f;
      if (col < 560) v = W_addr[(size_t)col * 512 + k0 + cc];
      else if (col < 1072) v = W_ea[(size_t)(col - 560) * 512 + k0 + cc];
      Ws[cc][rr] = v;
    }
    __syncthreads();
#pragma unroll
    for (int kk = 0; kk < 16; kk++) {
      float a0 = As[kk][ty * 2 + 0], a1 = As[kk][ty * 2 + 1];
      float w0 = Ws[kk][tx * 4 + 0], w1 = Ws[kk][tx * 4 + 1];
      float w2 = Ws[kk][tx * 4 + 2], w3 = Ws[kk][tx * 4 + 3];
      acc[0][0] += a0 * w0; acc[0][1] += a0 * w1; acc[0][2] += a0 * w2; acc[0][3] += a0 * w3;
      acc[1][0] += a1 * w0; acc[1][1] += a1 * w1; acc[1][2] += a1 * w2; acc[1][3] += a1 * w3;
    }
    __syncthreads();
  }
  for (int i = 0; i < 2; i++)
    for (int j = 0; j < 4; j++) {
      int col = col0 + tx * 4 + j;
      if (col < 1072) {
        float bias = col < 560 ? b_addr[col] : b_ea[col - 560];
        p_raw[(size_t)(row0 + ty * 2 + i) * 1072 + col] = acc[i][j] + bias;
      }
    }
}

// ---------------- per-b params: knorm/beta/gate/s/gamma + combo vectors + scalars
__global__ void params_kernel(const float* __restrict__ p_raw,
    float* __restrict__ knorm, float* __restrict__ betav,
    float* __restrict__ gatev, float* __restrict__ sv,
    float* __restrict__ gammav, float* __restrict__ combo,
    float* __restrict__ scal) {
  int b = blockIdx.x, m = threadIdx.x;
  const float* p = p_raw + (size_t)b * 1072;
  float kv[7];
#pragma unroll
  for (int hi = 0; hi < 7; hi++) {
    float k = tanhf(p[hi * 70 + m]);
    kv[hi] = k;
    float s = k * k;
#pragma unroll
    for (int d = 1; d < 64; d <<= 1) s += __shfl_xor(s, d);
    if (m == 0) {
      int hb = hi * BB + b;
      knorm[hb] = sqrtf(s);
      betav[hb] = softplusf(p[hi * 70 + 64]);
      gatev[hb] = sigf(p[hi * 70 + 65]);
      float a0 = p[hi * 70 + 66], a1 = p[hi * 70 + 67], a2 = p[hi * 70 + 68];
      float mm = fmaxf(a0, fmaxf(a1, a2));
      float e0 = expf(a0 - mm), e1 = expf(a1 - mm), e2 = expf(a2 - mm);
      float es = e0 + e1 + e2;
      sv[hb * 3 + 0] = e0 / es; sv[hb * 3 + 1] = e1 / es; sv[hb * 3 + 2] = e2 / es;
      gammav[hb] = 1.0f + softplusf(p[hi * 70 + 69]);
    }
  }
  float e1 = sigf(p[560 + 0 * 128 + m]),  a1v = tanhf(p[560 + 0 * 128 + 64 + m]);
  float e3 = sigf(p[560 + 1 * 128 + m]),  a3v = tanhf(p[560 + 1 * 128 + 64 + m]);
  float e5 = sigf(p[560 + 2 * 128 + m]),  a5v = tanhf(p[560 + 2 * 128 + 64 + m]);
  size_t bm = (size_t)b * 64 + m;
  combo[0 * 16384 + bm] = kv[0];  combo[1 * 16384 + bm] = kv[1];
  combo[2 * 16384 + bm] = kv[2];  combo[3 * 16384 + bm] = e1 * kv[2];
  combo[4 * 16384 + bm] = kv[3];  combo[5 * 16384 + bm] = e1 * kv[3];
  combo[6 * 16384 + bm] = a1v;    combo[7 * 16384 + bm] = e1 * a1v;
  combo[8 * 16384 + bm] = e1;     combo[9 * 16384 + bm] = e1 * e1;
  combo[10 * 16384 + bm] = kv[4]; combo[11 * 16384 + bm] = kv[5];
  combo[12 * 16384 + bm] = kv[6]; combo[13 * 16384 + bm] = e5 * kv[6];
  combo[14 * 16384 + bm] = a5v;   combo[15 * 16384 + bm] = e5 * a5v;
  combo[16 * 16384 + bm] = e5;    combo[17 * 16384 + bm] = e5 * e5;
  combo[18 * 16384 + bm] = e3;    combo[19 * 16384 + bm] = a3v;
  float s0 = a1v * kv[2], s1 = a1v * kv[3], s2 = a1v * a1v, s3 = a5v * kv[6], s4 = a5v * a5v;
#pragma unroll
  for (int d = 1; d < 64; d <<= 1) {
    s0 += __shfl_xor(s0, d); s1 += __shfl_xor(s1, d); s2 += __shfl_xor(s2, d);
    s3 += __shfl_xor(s3, d); s4 += __shfl_xor(s4, d);
  }
  if (m == 0) {
    scal[b * 8 + 0] = s0; scal[b * 8 + 1] = s1; scal[b * 8 + 2] = s2;
    scal[b * 8 + 3] = s3; scal[b * 8 + 4] = s4;
  }
}

#define CL(j, q) (*(const float4*)(cb + (j) * 64 + (q) * 4))

// ---------------- phase 1: LDS-staged coalesced. fp32 stream -> bf16 shadow + 9 planes
// grid (32 n-chunks, 256 b) x 256 thr. 128-row swizzled tile (32KB) -> 4 blocks/CU.
// Block x==0 also zeroes this b's slice of `reads` (replaces the memset dispatch).
__global__ __launch_bounds__(256) void phase1_kernel(
    const float* __restrict__ mem, const float* __restrict__ combo,
    const float* __restrict__ scal, const float* __restrict__ knorm,
    const float* __restrict__ betav, unsigned short* __restrict__ mem_bf,
    __half* __restrict__ P, float* __restrict__ reads) {
  __shared__ float cb[640];
  __shared__ float4 tile[128 * 16];   // 32 KB, XOR-swizzled rows
  int b = blockIdx.y, tid = threadIdx.x;
  for (int i = tid; i < 640; i += 256)
    cb[i] = combo[(size_t)(i >> 6) * 16384 + b * 64 + (i & 63)];
  if (blockIdx.x == 0)
    reads[(size_t)(tid >> 6) * 16384 + b * 64 + (tid & 63)] = 0.f;
  int n0 = blockIdx.x * 128;
  size_t bo = (size_t)b * NN;
  const float4* src = (const float4*)mem + (bo + n0) * 16;
  ushort4* dst = (ushort4*)mem_bf + (bo + n0) * 16;
#pragma unroll
  for (int i = 0; i < 8; i++) {
    int idx = tid + i * 256;
    float4 v = src[idx];
    int r = idx >> 4, q = idx & 15;
    tile[r * 16 + (q ^ (r & 15))] = v;
    ushort4 o;
    o.x = f2bf(v.x); o.y = f2bf(v.y); o.z = f2bf(v.z); o.w = f2bf(v.w);
    dst[idx] = o;
  }
  __syncthreads();
  float kn0 = knorm[b], be0 = betav[b];
  float kn1 = knorm[BB + b], be1 = betav[BB + b];
  float cak2 = scal[b * 8 + 0], cak3 = scal[b * 8 + 1], caa1 = scal[b * 8 + 2];
  int row = tid >> 1, half = tid & 1;
  float a[11];
#pragma unroll
  for (int k = 0; k < 11; k++) a[k] = 0.f;
#pragma unroll
  for (int j = 0; j < 8; j++) {
    int q = half * 8 + j;
    float4 v = tile[row * 16 + (q ^ (row & 15))];
    float4 sq = make_float4(v.x * v.x, v.y * v.y, v.z * v.z, v.w * v.w);
    a[0] += dot4(v, CL(0, q)); a[1] += dot4(v, CL(1, q));
    a[2] += dot4(v, CL(2, q)); a[3] += dot4(v, CL(3, q));
    a[4] += dot4(v, CL(4, q)); a[5] += dot4(v, CL(5, q));
    a[6] += dot4(v, CL(6, q)); a[7] += dot4(v, CL(7, q));
    a[8] += sq.x + sq.y + sq.z + sq.w;
    a[9] += dot4(sq, CL(8, q)); a[10] += dot4(sq, CL(9, q));
  }
#pragma unroll
  for (int k = 0; k < 11; k++) a[k] += __shfl_xor(a[k], 1);
  if (half == 0) {
    int n = n0 + row;
    float rn = sqrtf(a[8]);
    P[0 * PH + bo + n] = __float2half(be0 * a[0] / (rn * kn0 + EPSF));
    P[1 * PH + bo + n] = __float2half(be1 * a[1] / (rn * kn1 + EPSF));
    P[2 * PH + bo + n] = __float2half(a[2]);
    P[3 * PH + bo + n] = __float2half(a[3] - cak2);
    P[4 * PH + bo + n] = __float2half(a[4]);
    P[5 * PH + bo + n] = __float2half(a[5] - cak3);
    P[6 * PH + bo + n] = __float2half(a[8]);
    P[7 * PH + bo + n] = __float2half(a[9] - a[6]);
    P[8 * PH + bo + n] = __float2half(a[10] - 2.f * a[7] + caa1);
  }
}

// ---------------- chain: one (head,b) per block. score -> softmax -> interp -> shift -> sharpen -> w_g
// group 0: heads {0,1} SC-path | 1: heads {2,3} D-path u=w1 | 2: heads {4,5} SC-path | 3: head {6} D-path u=w5
__global__ __launch_bounds__(512) void chain_kernel(
    const __half* __restrict__ P, __half* __restrict__ w_g,
    const float* __restrict__ knorm, const float* __restrict__ betav,
    const float* __restrict__ gatev, const float* __restrict__ sv,
    const float* __restrict__ gammav, const float* __restrict__ prev_w,
    int group) {
  __shared__ float wg[NN];
  __shared__ float red[24];
  int b = blockIdx.x, hy = blockIdx.y, tid = threadIdx.x;
  int lane = tid & 63, wv = tid >> 6;
  int head, u_head = 0;
  const __half *SC = nullptr, *Da = nullptr, *Dbc = nullptr;
  const __half *S0p = nullptr, *T1p = nullptr, *T2p = nullptr;
  if (group == 0)      { head = hy;     SC = P + (size_t)hy * PH; }
  else if (group == 1) { head = 2 + hy; Da = P + (size_t)(2 + 2 * hy) * PH; Dbc = P + (size_t)(3 + 2 * hy) * PH;
                         S0p = P + 6 * PH; T1p = P + 7 * PH; T2p = P + 8 * PH; u_head = 1; }
  else if (group == 2) { head = 4 + hy; SC = P + (size_t)hy * PH; }
  else                 { head = 6;      Da = P + 2 * PH; Dbc = P + 3 * PH;
                         S0p = P + 4 * PH; T1p = P + 5 * PH; T2p = P + 6 * PH; u_head = 5; }
  int hb = head * BB + b;
  float kn = knorm[hb], be = betav[hb], ga = gatev[hb], gm = gammav[hb];
  float s0 = sv[hb * 3 + 0], s1 = sv[hb * 3 + 1], s2 = sv[hb * 3 + 2];
  size_t bo = (size_t)b * NN;
  const float* pw = prev_w + (size_t)head * PH + bo;
  const __half* ug = w_g + ((size_t)u_head * BB + b) * NN;
  __half* wout = w_g + ((size_t)head * BB + b) * NN;
  float sc[8];
  float mx = -1e30f;
#pragma unroll
  for (int i = 0; i < 8; i++) {
    int n = tid + i * 512;
    float scv;
    if (SC != nullptr) {
      scv = __half2float(SC[bo + n]);
    } else {
      float u = __half2float(ug[n]);
      float d = __half2float(Da[bo + n]) - u * __half2float(Dbc[bo + n]);
      float nn2 = __half2float(S0p[bo + n]) - 2.f * u * __half2float(T1p[bo + n])
                + u * u * __half2float(T2p[bo + n]);
      nn2 = fmaxf(nn2, 0.f);
      scv = be * d / (sqrtf(nn2) * kn + EPSF);
    }
    sc[i] = scv; mx = fmaxf(mx, scv);
  }
#pragma unroll
  for (int m = 1; m < 64; m <<= 1) mx = fmaxf(mx, __shfl_xor(mx, m));
  if (lane == 0) red[wv] = mx;
  __syncthreads();
  mx = red[0];
#pragma unroll
  for (int w = 1; w < 8; w++) mx = fmaxf(mx, red[w]);
  float sum = 0.f;
#pragma unroll
  for (int i = 0; i < 8; i++) { sc[i] = __expf(sc[i] - mx); sum += sc[i]; }
#pragma unroll
  for (int m = 1; m < 64; m <<= 1) sum += __shfl_xor(sum, m);
  if (lane == 0) red[8 + wv] = sum;
  __syncthreads();
  sum = 0.f;
#pragma unroll
  for (int w = 0; w < 8; w++) sum += red[8 + w];
  float inv = 1.0f / sum;
#pragma unroll
  for (int i = 0; i < 8; i++) {
    int n = tid + i * 512;
    wg[n] = ga * (sc[i] * inv) + (1.f - ga) * pw[n];
  }
  __syncthreads();
  float wp[8];
  float sum2 = 0.f;
#pragma unroll
  for (int i = 0; i < 8; i++) {
    int n = tid + i * 512;
    float wsv = s0 * wg[(n + NN - 1) & (NN - 1)] + s1 * wg[n] + s2 * wg[(n + 1) & (NN - 1)];
    wp[i] = __powf(wsv, gm);
    sum2 += wp[i];
  }
#pragma unroll
  for (int m = 1; m < 64; m <<= 1) sum2 += __shfl_xor(sum2, m);
  if (lane == 0) red[16 + wv] = sum2;
  __syncthreads();
  sum2 = 0.f;
#pragma unroll
  for (int w = 0; w < 8; w++) sum2 += red[16 + w];
  float invs = 1.0f / (sum2 + EPSF);
#pragma unroll
  for (int i = 0; i < 8; i++) {
    int n = tid + i * 512;
    wout[n] = __float2half(wp[i] * invs);
  }
}

// ---------------- phase 2: LDS-staged coalesced. bf16 stream, m2 in regs, 7 planes
__global__ __launch_bounds__(256) void phase2_kernel(
    const unsigned short* __restrict__ mem_bf, const float* __restrict__ combo,
    const float* __restrict__ scal, const float* __restrict__ knorm,
    const float* __restrict__ betav, const __half* __restrict__ w_g,
    __half* __restrict__ P) {
  __shared__ float cb[1280];
  __shared__ uint4 tileb[128 * 8];
  int b = blockIdx.y, tid = threadIdx.x;
  for (int i = tid; i < 1280; i += 256)
    cb[i] = combo[(size_t)(i >> 6) * 16384 + b * 64 + (i & 63)];
  int n0 = blockIdx.x * 128;
  size_t bo = (size_t)b * NN;
  const uint4* src = (const uint4*)mem_bf + (bo + n0) * 8;
#pragma unroll
  for (int i = 0; i < 4; i++) {
    int idx = tid + i * 256;
    uint4 u = src[idx];
    int r = idx >> 3, g = idx & 7;
    tileb[r * 8 + (g ^ (r & 7))] = u;
  }
  __syncthreads();
  float kn4 = knorm[4 * BB + b], be4 = betav[4 * BB + b];
  float kn5 = knorm[5 * BB + b], be5 = betav[5 * BB + b];
  float cak6 = scal[b * 8 + 3], caa5 = scal[b * 8 + 4];
  int row = tid >> 1, half = tid & 1;
  int n = n0 + row;
  float u1 = __half2float(w_g[((size_t)1 * BB + b) * NN + n]);
  float u3 = __half2float(w_g[((size_t)3 * BB + b) * NN + n]);
  float t[9];
#pragma unroll
  for (int k = 0; k < 9; k++) t[k] = 0.f;
#pragma unroll
  for (int j = 0; j < 4; j++) {
    int g = half * 4 + j;
    uint4 uv = tileb[row * 8 + (g ^ (row & 7))];
#pragma unroll
    for (int h = 0; h < 2; h++) {
      unsigned int pa = h ? uv.z : uv.x;
      unsigned int pb = h ? uv.w : uv.y;
      float4 v;
      v.x = bf2f(pa & 0xFFFFu); v.y = bf2f(pa >> 16);
      v.z = bf2f(pb & 0xFFFFu); v.w = bf2f(pb >> 16);
      int q = g * 2 + h;
      float4 e1v = CL(8, q), a1v = CL(6, q), e3v = CL(18, q), a3v = CL(19, q);
      float4 m1, m2;
      m1.x = v.x * (1.f - u1 * e1v.x) + u1 * a1v.x;
      m1.y = v.y * (1.f - u1 * e1v.y) + u1 * a1v.y;
      m1.z = v.z * (1.f - u1 * e1v.z) + u1 * a1v.z;
      m1.w = v.w * (1.f - u1 * e1v.w) + u1 * a1v.w;
      m2.x = m1.x * (1.f - u3 * e3v.x) + u3 * a3v.x;
      m2.y = m1.y * (1.f - u3 * e3v.y) + u3 * a3v.y;
      m2.z = m1.z * (1.f - u3 * e3v.z) + u3 * a3v.z;
      m2.w = m1.w * (1.f - u3 * e3v.w) + u3 * a3v.w;
      float4 sq = make_float4(m2.x * m2.x, m2.y * m2.y, m2.z * m2.z, m2.w * m2.w);
      t[0] += dot4(m2, CL(10, q)); t[1] += dot4(m2, CL(11, q));
      t[2] += dot4(m2, CL(12, q)); t[3] += dot4(m2, CL(13, q));
      t[4] += dot4(m2, CL(14, q)); t[5] += dot4(m2, CL(15, q));
      t[6] += sq.x + sq.y + sq.z + sq.w;
      t[7] += dot4(sq, CL(16, q)); t[8] += dot4(sq, CL(17, q));
    }
  }
#pragma unroll
  for (int k = 0; k < 9; k++) t[k] += __shfl_xor(t[k], 1);
  if (half == 0) {
    float rn = sqrtf(t[6]);
    P[0 * PH + bo + n] = __float2half(be4 * t[0] / (rn * kn4 + EPSF));
    P[1 * PH + bo + n] = __float2half(be5 * t[1] / (rn * kn5 + EPSF));
    P[2 * PH + bo + n] = __float2half(t[2]);
    P[3 * PH + bo + n] = __float2half(t[3] - cak6);
    P[4 * PH + bo + n] = __float2half(t[6]);
    P[5 * PH + bo + n] = __float2half(t[7] - t[4]);
    P[6 * PH + bo + n] = __float2half(t[8] - 2.f * t[5] + caa5);
  }
}

// ---------------- phase 3: the four reads. grid (8,256) x 256 thr, atomicAdd partials
__global__ __launch_bounds__(256) void phase3_kernel(
    const unsigned short* __restrict__ mem_bf, const float* __restrict__ combo,
    const __half* __restrict__ w_g, float* __restrict__ reads) {
  __shared__ float cb[1280];
  __shared__ __half ws[7 * 512];
  __shared__ float sred[4 * 4 * 16 * 4];
  int b = blockIdx.y, chunk = blockIdx.x, tid = threadIdx.x;
  for (int i = tid; i < 1280; i += 256)
    cb[i] = combo[(size_t)(i >> 6) * 16384 + b * 64 + (i & 63)];
  int nbase = chunk * 512;
  for (int i = tid; i < 7 * 512; i += 256) {
    int hh = i >> 9, nn = i & 511;
    ws[i] = w_g[((size_t)hh * BB + b) * NN + nbase + nn];
  }
  __syncthreads();
  int wv = tid >> 6, lane = tid & 63, q = lane & 15, rl = lane >> 4;
  float4 e1v = CL(8, q), a1v = CL(6, q), e3v = CL(18, q), a3v = CL(19, q);
  float4 e5v = CL(16, q), a5v = CL(14, q);
  size_t bo = (size_t)b * NN;
  const ushort4* mbr = (const ushort4*)mem_bf + bo * 16;
  float A[4][4];
#pragma unroll
  for (int j = 0; j < 4; j++)
#pragma unroll
    for (int cmp = 0; cmp < 4; cmp++) A[j][cmp] = 0.f;
#pragma unroll 4
  for (int t = 0; t < 32; t++) {
    int nl = t * 16 + wv * 4 + rl;
    int n = nbase + nl;
    ushort4 uv = mbr[(size_t)n * 16 + q];
    float vx = bf2f(uv.x), vy = bf2f(uv.y), vz = bf2f(uv.z), vw = bf2f(uv.w);
    float w0v = __half2float(ws[0 * 512 + nl]);
    float u1  = __half2float(ws[1 * 512 + nl]);
    float w2v = __half2float(ws[2 * 512 + nl]);
    float u3  = __half2float(ws[3 * 512 + nl]);
    float w4v = __half2float(ws[4 * 512 + nl]);
    float u5  = __half2float(ws[5 * 512 + nl]);
    float w6v = __half2float(ws[6 * 512 + nl]);
    A[0][0] += w0v * vx; A[0][1] += w0v * vy; A[0][2] += w0v * vz; A[0][3] += w0v * vw;
    float m1x = vx * (1.f - u1 * e1v.x) + u1 * a1v.x;
    float m1y = vy * (1.f - u1 * e1v.y) + u1 * a1v.y;
    float m1z = vz * (1.f - u1 * e1v.z) + u1 * a1v.z;
    float m1w = vw * (1.f - u1 * e1v.w) + u1 * a1v.w;
    A[1][0] += w2v * m1x; A[1][1] += w2v * m1y; A[1][2] += w2v * m1z; A[1][3] += w2v * m1w;
    float m2x = m1x * (1.f - u3 * e3v.x) + u3 * a3v.x;
    float m2y = m1y * (1.f - u3 * e3v.y) + u3 * a3v.y;
    float m2z = m1z * (1.f - u3 * e3v.z) + u3 * a3v.z;
    float m2w = m1w * (1.f - u3 * e3v.w) + u3 * a3v.w;
    A[2][0] += w4v * m2x; A[2][1] += w4v * m2y; A[2][2] += w4v * m2z; A[2][3] += w4v * m2w;
    float m3x = m2x * (1.f - u5 * e5v.x) + u5 * a5v.x;
    float m3y = m2y * (1.f - u5 * e5v.y) + u5 * a5v.y;
    float m3z = m2z * (1.f - u5 * e5v.z) + u5 * a5v.z;
    float m3w = m2w * (1.f - u5 * e5v.w) + u5 * a5v.w;
    A[3][0] += w6v * m3x; A[3][1] += w6v * m3y; A[3][2] += w6v * m3z; A[3][3] += w6v * m3w;
  }
#pragma unroll
  for (int j = 0; j < 4; j++)
#pragma unroll
    for (int cmp = 0; cmp < 4; cmp++) {
      float x = A[j][cmp];
      x += __shfl_xor(x, 16);
      x += __shfl_xor(x, 32);
      A[j][cmp] = x;
    }
  if (rl == 0)
#pragma unroll
    for (int j = 0; j < 4; j++)
#pragma unroll
      for (int cmp = 0; cmp < 4; cmp++)
        sred[((j * 4 + wv) * 16 + q) * 4 + cmp] = A[j][cmp];
  __syncthreads();
  if (tid < 256) {
    int j = tid >> 6, qq = (tid >> 2) & 15, cc = tid & 3;
    float s = 0.f;
#pragma unroll
    for (int w = 0; w < 4; w++) s += sred[((j * 4 + w) * 16 + qq) * 4 + cc];
    atomicAdd(&reads[(size_t)j * 16384 + b * 64 + qq * 4 + cc], s);
  }
}

// ---------------- out = sigmoid([h|reads] @ W_out^T + b_out) : [256][64]
__global__ __launch_bounds__(256) void gemm_out_kernel(
    const float* __restrict__ h, const float* __restrict__ reads,
    const float* __restrict__ W_out, const float* __restrict__ b_out,
    float* __restrict__ out) {
  __shared__ float As[16][33];
  __shared__ float Ws[16][65];
  int tid = threadIdx.x, tx = tid & 15, ty = tid >> 4;
  int row0 = blockIdx.y * 32;
  float acc[2][4] = {{0,0,0,0},{0,0,0,0}};
  for (int k0 = 0; k0 < 768; k0 += 16) {
    for (int i = tid; i < 32 * 16; i += 256) {
      int rr = i >> 4, cc = i & 15;
      int row = row0 + rr, k = k0 + cc;
      float v;
      if (k < 512) v = h[row * 512 + k];
      else { int slot = (k - 512) >> 6, m = (k - 512) & 63; v = reads[((size_t)slot * 256 + row) * 64 + m]; }
      As[cc][rr] = v;
    }
    for (int i = tid; i < 64 * 16; i += 256) {
      int rr = i >> 4, cc = i & 15;
      Ws[cc][rr] = W_out[(size_t)rr * 768 + k0 + cc];
    }
    __syncthreads();
#pragma unroll
    for (int kk = 0; kk < 16; kk++) {
      float a0 = As[kk][ty * 2 + 0], a1 = As[kk][ty * 2 + 1];
      float w0 = Ws[kk][tx * 4 + 0], w1 = Ws[kk][tx * 4 + 1];
      float w2 = Ws[kk][tx * 4 + 2], w3 = Ws[kk][tx * 4 + 3];
      acc[0][0] += a0 * w0; acc[0][1] += a0 * w1; acc[0][2] += a0 * w2; acc[0][3] += a0 * w3;
      acc[1][0] += a1 * w0; acc[1][1] += a1 * w1; acc[1][2] += a1 * w2; acc[1][3] += a1 * w3;
    }
    __syncthreads();
  }
  for (int i = 0; i < 2; i++)
    for (int j = 0; j < 4; j++) {
      int cc = tx * 4 + j;
      out[(size_t)(row0 + ty * 2 + i) * 64 + cc] = sigf(acc[i][j] + b_out[cc]);
    }
}

extern "C" void kernel_launch(void* const* d_in, const int* in_sizes, int n_in,
                              void* d_out, int out_size, void* d_ws, size_t ws_size,
                              hipStream_t stream) {
  const float* in_data = (const float*)d_in[0];
  const float* memory  = (const float*)d_in[1];
  const float* h0      = (const float*)d_in[2];
  const float* c0      = (const float*)d_in[3];
  const float* prev_w  = (const float*)d_in[4];
  const float* prev_r  = (const float*)d_in[5];
  const float* W_ih    = (const float*)d_in[6];
  const float* b_ih    = (const float*)d_in[7];
  const float* W_hh    = (const float*)d_in[8];
  const float* b_hh    = (const float*)d_in[9];
  const float* W_out   = (const float*)d_in[10];
  const float* b_out   = (const float*)d_in[11];
  const float* W_addr  = (const float*)d_in[12];
  const float* b_addr  = (const float*)d_in[13];
  const float* W_ea    = (const float*)d_in[14];
  const float* b_ea    = (const float*)d_in[15];
  float* out = (float*)d_out;
  (void)in_sizes; (void)n_in; (void)out_size; (void)ws_size;

  float* ws = (float*)d_ws;
  size_t off = 0;
  auto alloc = [&](size_t n) { float* p = ws + off; off += (n + 63) & ~(size_t)63; return p; };
  float* gates  = alloc(256 * 2048);
  float* cbuf   = alloc(256 * 512);
  float* hbuf   = alloc(256 * 512);
  float* p_raw  = alloc(256 * 1072);
  float* knorm  = alloc(8 * 256);
  float* betav  = alloc(8 * 256);
  float* gatev  = alloc(8 * 256);
  float* sv     = alloc(8 * 256 * 3);
  float* gammav = alloc(8 * 256);
  float* combo  = alloc(20 * 16384);
  float* scal   = alloc(256 * 8);
  __half* P     = (__half*)alloc(9 * PH / 2);           // 9 fp16 planes
  float* reads  = alloc(4 * 16384);                     // zeroed inside phase1
  unsigned short* mem_bf = (unsigned short*)alloc(33554432); // 128 MB bf16 copy
  __half* w_g   = (__half*)alloc(7 * BB * NN / 2);      // 7 head-weight planes fp16

  gemm_gates_kernel<<<dim3(32, 8), 256, 0, stream>>>(in_data, prev_r, h0, W_ih, W_hh, b_ih, b_hh, gates);
  lstm_elem_kernel<<<(256 * 512 + 255) / 256, 256, 0, stream>>>(gates, c0, cbuf, hbuf);
  gemm_heads_kernel<<<dim3(17, 8), 256, 0, stream>>>(cbuf, W_addr, W_ea, b_addr, b_ea, p_raw);
  params_kernel<<<256, 64, 0, stream>>>(p_raw, knorm, betav, gatev, sv, gammav, combo, scal);

  phase1_kernel<<<dim3(32, 256), 256, 0, stream>>>(memory, combo, scal, knorm, betav, mem_bf, P, reads);
  chain_kernel<<<dim3(256, 2), 512, 0, stream>>>(P, w_g, knorm, betav, gatev, sv, gammav, prev_w, 0);
  chain_kernel<<<dim3(256, 2), 512, 0, stream>>>(P, w_g, knorm, betav, gatev, sv, gammav, prev_w, 1);
  phase2_kernel<<<dim3(32, 256), 256, 0, stream>>>(mem_bf, combo, scal, knorm, betav, w_g, P);
  chain_kernel<<<dim3(256, 2), 512, 0, stream>>>(P, w_g, knorm, betav, gatev, sv, gammav, prev_w, 2);
  chain_kernel<<<dim3(256, 1), 512, 0, stream>>>(P, w_g, knorm, betav, gatev, sv, gammav, prev_w, 3);
  phase3_kernel<<<dim3(8, 256), 256, 0, stream>>>(mem_bf, combo, w_g, reads);

  gemm_out_kernel<<<dim3(1, 8), 256, 0, stream>>>(hbuf, reads, W_out, b_out, out);
}